// Round 6
// baseline (409.176 us; speedup 1.0000x reference)
//
#include <hip/hip_runtime.h>
#include <math.h>

// E-Langevin sampler, fully fused: one kernel runs all 5 scan steps.
//  * rows independent -> one wave owns one row for the whole scan
//  * x binary -> x@W is a gather-sum of W rows; x_delta@W is an
//    incremental sparse update (~19.5 flipped bits/row/step)
//  * branchless sigmoid: e=expf(-|t|), num=(t>=0)?1:e, num/(1+e) --
//    operation-identical to the branchy version (bitwise same result)
//    but avoids executing BOTH divergent paths per mixed wave
//  * gathers run through a flat 8-slot pipeline across all 4 bit-masks
//    (dummy slots use s=0 -> fma(0,w,y)==y bitwise); accumulation order
//    stays i-major, bit-ascending == previous passing rounds
//  * step gather: first 8 loads issue right after the ballots and fly
//    during the logf-heavy remainder of phase 1
//  * rr/noise/x/xa/out accesses non-temporal so ~200MB of streaming
//    traffic does not evict W (256KB) from the XCD L2s
//  * absmax must stay 0.0 -- every fp op & order bitwise preserved

namespace {

constexpr int kB = 16384;
constexpr int kD = 256;
constexpr int kSteps = 5;

typedef float v2f __attribute__((ext_vector_type(2)));
typedef float v4f __attribute__((ext_vector_type(4)));

__device__ __forceinline__ v4f nt_load4(const float* p) {
  return __builtin_nontemporal_load(reinterpret_cast<const v4f*>(p));
}
__device__ __forceinline__ void nt_store4(float* p, v4f v) {
  __builtin_nontemporal_store(v, reinterpret_cast<v4f*>(p));
}

__device__ __forceinline__ float wave_sum(float v) {
#pragma unroll
  for (int off = 32; off > 0; off >>= 1) v += __shfl_xor(v, off, 64);
  return v;
}

// Bitwise-identical to: t>=0 ? 1/(1+expf(-t)) : expf(t)/(1+expf(t)),
// but single-path (no divergence): exp arg is -|t| in both cases and the
// one division uses the same operands either way.
__device__ __forceinline__ float sigmoid_f(float t) {
  const float e = expf(-fabsf(t));
  const float num = (t >= 0.0f) ? 1.0f : e;
  return num / (1.0f + e);
}

// Extract next up-to-8 set bits across 4 masks (i-major, bit-ascending).
// Empty slots -> d=0, s=0 (dummy load, zero contribution).
template <bool SIGNED>
__device__ __forceinline__ void extract8(
    unsigned long long& m0, unsigned long long& m1,
    unsigned long long& m2, unsigned long long& m3,
    const unsigned long long* smk, int* dq, float* sq) {
#pragma unroll
  for (int q = 0; q < 8; ++q) {
    int d = -1;
    if (m0) { const int j = __builtin_ctzll(m0); m0 &= m0 - 1; d = 4 * j; }
    else if (m1) { const int j = __builtin_ctzll(m1); m1 &= m1 - 1; d = 4 * j + 1; }
    else if (m2) { const int j = __builtin_ctzll(m2); m2 &= m2 - 1; d = 4 * j + 2; }
    else if (m3) { const int j = __builtin_ctzll(m3); m3 &= m3 - 1; d = 4 * j + 3; }
    if (d >= 0) {
      sq[q] = SIGNED ? ((((smk[d & 3] >> (d >> 2)) & 1ull) ? -1.0f : 1.0f)) : 1.0f;
      dq[q] = d;
    } else {
      dq[q] = 0;
      sq[q] = 0.0f;
    }
  }
}

__device__ __forceinline__ void load8(const float* Wlane, const int* dq, float4* w) {
#pragma unroll
  for (int q = 0; q < 8; ++q)
    w[q] = *reinterpret_cast<const float4*>(Wlane + (size_t)dq[q] * kD);
}

// fma(s,w,y): s=1 -> bitwise == y+w ; s=0 -> y unchanged ; s=-1 -> y-w.
__device__ __forceinline__ void acc8(const float4* w, const float* sq,
                                     v2f& ylo, v2f& yhi) {
#pragma unroll
  for (int q = 0; q < 8; ++q) {
    const v2f sv = {sq[q], sq[q]};
    ylo = __builtin_elementwise_fma(sv, (v2f){w[q].x, w[q].y}, ylo);
    yhi = __builtin_elementwise_fma(sv, (v2f){w[q].z, w[q].w}, yhi);
  }
}

__global__ __launch_bounds__(256) void els_fused(
    const float* __restrict__ x_in, const float* __restrict__ xa_in,
    const float* __restrict__ W, const float* __restrict__ bvec,
    const float* __restrict__ rr, const float* __restrict__ noise,
    const float* __restrict__ accept_u, float* __restrict__ out) {
  const int lane = threadIdx.x & 63;
  const int row = blockIdx.x * 4 + (threadIdx.x >> 6);  // 4 waves/block
  const int c0 = lane << 2;  // this lane owns columns c0..c0+3
  const float* Wl = W + c0;

  const v4f x4 = nt_load4(x_in + (size_t)row * kD + c0);
  const v4f a4 = nt_load4(xa_in + (size_t)row * kD + c0);
  const float4 b4 = *reinterpret_cast<const float4*>(bvec + c0);
  float xv[4] = {x4.x, x4.y, x4.z, x4.w};
  float xa[4] = {a4.x, a4.y, a4.z, a4.w};
  const float bv[4] = {b4.x, b4.y, b4.z, b4.w};
  v2f y01 = {0.0f, 0.0f}, y23 = {0.0f, 0.0f};

  // prefetch step 0 inputs (latency hidden behind the init gather)
  v4f r4 = nt_load4(rr + (size_t)row * kD + c0);
  v4f n4 = nt_load4(noise + (size_t)row * kD + c0);
  float u = accept_u[row];

  // ---- init: y = x @ W, gather of W rows where x[d]==1 ----
  {
    unsigned long long m0 = __ballot(xv[0] > 0.5f);
    unsigned long long m1 = __ballot(xv[1] > 0.5f);
    unsigned long long m2 = __ballot(xv[2] > 0.5f);
    unsigned long long m3 = __ballot(xv[3] > 0.5f);
    int rem = __popcll(m0) + __popcll(m1) + __popcll(m2) + __popcll(m3);
    while (rem > 0) {
      int dq[8]; float sq[8]; float4 w[8];
      extract8<false>(m0, m1, m2, m3, nullptr, dq, sq);
      load8(Wl, dq, w);
      acc8(w, sq, y01, y23);
      rem -= 8;
    }
  }

  for (int step = 0; step < kSteps; ++step) {
    // consume this step's prefetched inputs
    const float rrv[4] = {r4.x, r4.y, r4.z, r4.w};
    const float nzv[4] = {n4.x, n4.y, n4.z, n4.w};
    const float ucur = u;

    // prefetch NEXT step's inputs (issued now, consumed next iteration)
    const int sn = (step + 1 < kSteps) ? step + 1 : step;
    const size_t offn = ((size_t)sn * kB + row) * kD + c0;
    r4 = nt_load4(rr + offn);
    n4 = nt_load4(noise + offn);
    u = accept_u[(size_t)sn * kB + row];

    const float yv[4] = {y01.x, y01.y, y23.x, y23.y};

    // ---- phase 1a: flip probabilities + ballots only ----
    float ga[4], p[4];
    bool ind[4];
    unsigned long long fm[4], sm[4];
#pragma unroll
    for (int i = 0; i < 4; ++i) {
      ga[i] = (xv[i] - xa[i]) / 1.0e4f;                     // agrad, ETA=1e4
      const float sgn = 1.0f - 2.0f * xv[i];                // -(2x-1)
      const float gm = (yv[i] + bv[i] - ga[i]) * sgn / 2.0f;  // TEMP=2
      p[i] = sigmoid_f(gm - 2.5f);                          // term2=1/(2*0.2)
      ind[i] = rrv[i] < p[i];
      fm[i] = __ballot(ind[i]);
      sm[i] = __ballot(xv[i] > 0.5f);  // flip 1->0 subtracts the W row
    }

    // ---- issue first 8 gather loads; they fly during phase 1b ----
    unsigned long long g0 = fm[0], g1 = fm[1], g2 = fm[2], g3 = fm[3];
    int rem = __popcll(g0) + __popcll(g1) + __popcll(g2) + __popcll(g3);
    int dq[8]; float sq[8]; float4 w[8];
    extract8<true>(g0, g1, g2, g3, sm, dq, sq);
    load8(Wl, dq, w);

    // ---- phase 1b: proposal state + forward log-probs ----
    float xd[4], xda[4];
    float s_lpf = 0.f, s_xy = 0.f, s_xb = 0.f, s_sqc = 0.f, s_fwd = 0.f;
#pragma unroll
    for (int i = 0; i < 4; ++i) {
      xd[i] = ind[i] ? 1.0f - xv[i] : xv[i];
      xda[i] = xa[i] + 0.25f * ga[i] + 0.70710678118654752f * nzv[i];
      const float pr = ind[i] ? p[i] : 1.0f - p[i];
      s_lpf += logf(pr + 1e-10f);
      s_xy += xv[i] * yv[i];
      s_xb += xv[i] * bv[i];
      const float dc = xv[i] - xa[i];
      s_sqc += dc * dc;
      const float fw = xda[i] - (xa[i] + 0.25f * ga[i]);
      s_fwd += fw * fw;
    }

    // ---- y2 = x_delta @ W: accumulate first 8, then remaining ----
    v2f y2lo = y01, y2hi = y23;
    acc8(w, sq, y2lo, y2hi);
    rem -= 8;
    while (rem > 0) {
      extract8<true>(g0, g1, g2, g3, sm, dq, sq);
      load8(Wl, dq, w);
      acc8(w, sq, y2lo, y2hi);
      rem -= 8;
    }

    const float y2v[4] = {y2lo.x, y2lo.y, y2hi.x, y2hi.y};
    float s_lpr = 0.f, s_xdy = 0.f, s_xdb = 0.f, s_sqn = 0.f, s_rev = 0.f;
#pragma unroll
    for (int i = 0; i < 4; ++i) {
      const float ga2 = (xd[i] - xda[i]) / 1.0e4f;
      const float sgn2 = 1.0f - 2.0f * xd[i];
      const float gm2 = (y2v[i] + bv[i] - ga2) * sgn2 / 2.0f;
      const float p2 = sigmoid_f(gm2 - 2.5f);
      const float pr2 = ind[i] ? p2 : 1.0f - p2;
      s_lpr += logf(pr2 + 1e-10f);
      s_xdy += xd[i] * y2v[i];
      s_xdb += xd[i] * bv[i];
      const float dn = xd[i] - xda[i];
      s_sqn += dn * dn;
      const float rv = xa[i] - (xda[i] + 0.25f * ga2);
      s_rev += rv * rv;
    }

    // row reductions (wave = row)
    s_lpf = wave_sum(s_lpf);
    s_lpr = wave_sum(s_lpr);
    s_xy = wave_sum(s_xy);
    s_xb = wave_sum(s_xb);
    s_xdy = wave_sum(s_xdy);
    s_xdb = wave_sum(s_xdb);
    s_sqc = wave_sum(s_sqc);
    s_sqn = wave_sum(s_sqn);
    s_rev = wave_sum(s_rev);
    s_fwd = wave_sum(s_fwd);

    const float E_cur = 0.5f * s_xy + s_xb;
    const float E_new = 0.5f * s_xdy + s_xdb;
    const float m_term = (E_new - s_sqn / 2.0e4f) - (E_cur - s_sqc / 2.0e4f);
    // add_rev = s_rev / (-2*ALPHA_A) = -s_rev ; add_fwd = -s_fwd
    const float la = m_term - s_rev + s_fwd + s_lpr - s_lpf;
    const bool acc = la > logf(ucur);

#pragma unroll
    for (int i = 0; i < 4; ++i) {
      xv[i] = acc ? xd[i] : xv[i];
      xa[i] = acc ? xda[i] : xa[i];
    }
    y01 = acc ? y2lo : y01;
    y23 = acc ? y2hi : y23;
  }

  const v4f ox = {xv[0], xv[1], xv[2], xv[3]};
  const v4f oa = {xa[0], xa[1], xa[2], xa[3]};
  nt_store4(out + (size_t)row * kD + c0, ox);
  nt_store4(out + (size_t)kB * kD + (size_t)row * kD + c0, oa);
}

}  // namespace

extern "C" void kernel_launch(void* const* d_in, const int* in_sizes, int n_in,
                              void* d_out, int out_size, void* d_ws, size_t ws_size,
                              hipStream_t stream) {
  const float* x = (const float*)d_in[0];
  const float* xa = (const float*)d_in[1];
  const float* W = (const float*)d_in[2];
  const float* b = (const float*)d_in[3];
  const float* rr = (const float*)d_in[4];
  const float* noise = (const float*)d_in[5];
  const float* au = (const float*)d_in[6];
  float* out = (float*)d_out;

  dim3 grid(kB / 4);
  dim3 block(256);
  hipLaunchKernelGGL(els_fused, grid, block, 0, stream, x, xa, W, b, rr, noise,
                     au, out);
}